// Round 4
// baseline (269.810 us; speedup 1.0000x reference)
//
#include <hip/hip_runtime.h>

typedef float f32x4 __attribute__((ext_vector_type(4)));

// ---------------------------------------------------------------------------
// Kernel A: per source column b, mark last occurrence of each vocab id.
// vlast[l*B+b] = sources[l*B+b] if l is the LAST occurrence of that id in
// column b, else -1. Only B columns exist (rows share columns mod B).
// ---------------------------------------------------------------------------
#define LMAX 1024

__global__ __launch_bounds__(256) void mask_kernel(
    const int* __restrict__ sources, int* __restrict__ vlast, int L, int B)
{
    const int b = blockIdx.x;
    __shared__ int s_col[LMAX];
    const bool use_lds = (L <= LMAX);
    if (use_lds) {
        for (int l = threadIdx.x; l < L; l += blockDim.x)
            s_col[l] = sources[(size_t)l * B + b];
    }
    __syncthreads();
    for (int l = threadIdx.x; l < L; l += blockDim.x) {
        const int v = use_lds ? s_col[l] : sources[(size_t)l * B + b];
        int keep = v;
        if (use_lds) {
            for (int l2 = l + 1; l2 < L; ++l2)
                if (s_col[l2] == v) { keep = -1; break; }
        } else {
            for (int l2 = l + 1; l2 < L; ++l2)
                if (sources[(size_t)l2 * B + b] == v) { keep = -1; break; }
        }
        vlast[(size_t)l * B + b] = keep;
    }
}

// ---------------------------------------------------------------------------
// Kernel B: streaming scale  out[row,:] = pg[row] * vd[row,:]
// CPR chunks per row -> rows*CPR blocks (64 blocks/CU at CPR=8): continuous
// wave supply, small per-block work, plain f32x4 stores (the 6.8 TB/s fill
// uses plain stores; NT stores dropped).
// ---------------------------------------------------------------------------
__global__ __launch_bounds__(256) void scale_kernel(
    const float* __restrict__ vd, const float* __restrict__ pgs,
    float* __restrict__ out, int V, int CPR)
{
    const int bid   = blockIdx.x;
    const int row   = bid / CPR;
    const int chunk = bid - row * CPR;
    const int tid   = threadIdx.x;
    const size_t base = (size_t)row * (size_t)V;
    const float pg = pgs[row];

    // peel to 16B alignment (V odd -> row bases rotate mod 4 elements)
    const int mis  = (int)(base & 3);
    const int pre  = mis ? (4 - mis) : 0;
    const int preN = pre < V ? pre : V;
    const int nvec = (V - preN) >> 2;            // # of aligned f32x4
    const int per  = (nvec + CPR - 1) / CPR;     // vec elems per chunk
    const int v0   = chunk * per;
    const int v1   = (v0 + per < nvec) ? (v0 + per) : nvec;

    const f32x4* __restrict__ v4 = (const f32x4*)(vd + base + preN);
    f32x4* __restrict__ o4       = (f32x4*)(out + base + preN);
    for (int i = v0 + tid; i < v1; i += 256) {
        f32x4 x = v4[i];
        x *= pg;
        o4[i] = x;
    }
    if (chunk == 0)
        for (int j = tid; j < preN; j += 256)
            out[base + j] = pg * vd[base + j];
    if (chunk == CPR - 1)
        for (int j = preN + (nvec << 2) + tid; j < V; j += 256)
            out[base + j] = pg * vd[base + j];
}

// ---------------------------------------------------------------------------
// Kernel C: scatter. Mask guarantees one writer per (row, vocab slot):
// out[row, v] = pg*vd[row, v] + (1-pg)*attns[row, l].
// ---------------------------------------------------------------------------
__global__ __launch_bounds__(256) void scatter_kernel(
    const float* __restrict__ vd, const float* __restrict__ attns,
    const float* __restrict__ pgs, const int* __restrict__ vlast,
    float* __restrict__ out, int V, int L, int B)
{
    const int row = blockIdx.x;
    const int b = row % B;
    const float pg = pgs[row];
    const float gate = 1.0f - pg;
    const size_t base = (size_t)row * (size_t)V;
    for (int l = threadIdx.x; l < L; l += 256) {
        const int v = vlast[(size_t)l * B + b];
        if (v >= 0 && v < V)
            out[base + v] = fmaf(pg, vd[base + v],
                                 gate * attns[(size_t)row * L + l]);
    }
}

// ---------------------------------------------------------------------------
// Fallback (round-1 fused kernel) if d_ws is too small for the mask.
// ---------------------------------------------------------------------------
__global__ __launch_bounds__(256) void fused_fallback_kernel(
    const float* __restrict__ vocab_ds, const float* __restrict__ attns,
    const float* __restrict__ p_gens, const int* __restrict__ sources,
    float* __restrict__ out, int V, int L, int B)
{
    const int row = blockIdx.x;
    const int tid = threadIdx.x;
    const size_t base = (size_t)row * (size_t)V;
    const float pg = p_gens[row];

    const int mis  = (int)(base & 3);
    const int pre  = mis ? (4 - mis) : 0;
    const int preN = pre < V ? pre : V;
    for (int j = tid; j < preN; j += blockDim.x)
        out[base + j] = pg * vocab_ds[base + j];
    const int nvec = (V - preN) >> 2;
    const f32x4* __restrict__ v4 = (const f32x4*)(vocab_ds + base + preN);
    f32x4* __restrict__ o4       = (f32x4*)(out + base + preN);
    for (int i = tid; i < nvec; i += blockDim.x) {
        f32x4 x = v4[i];
        x *= pg;
        o4[i] = x;
    }
    for (int j = preN + (nvec << 2) + tid; j < V; j += blockDim.x)
        out[base + j] = pg * vocab_ds[base + j];

    __shared__ int s_src[512];
    const int b = row % B;
    const bool use_lds = (L <= 512);
    if (use_lds) {
        for (int l = tid; l < L; l += blockDim.x)
            s_src[l] = sources[(size_t)l * B + b];
    }
    __syncthreads();
    const float gate = 1.0f - pg;
    for (int l = tid; l < L; l += blockDim.x) {
        const int v = use_lds ? s_src[l] : sources[(size_t)l * B + b];
        if (v < 0 || v >= V) continue;
        bool last = true;
        for (int l2 = l + 1; l2 < L; ++l2) {
            const int v2 = use_lds ? s_src[l2] : sources[(size_t)l2 * B + b];
            if (v2 == v) { last = false; break; }
        }
        if (last) {
            const float a = gate * attns[(size_t)row * L + l];
            out[base + v] = pg * vocab_ds[base + v] + a;
        }
    }
}

extern "C" void kernel_launch(void* const* d_in, const int* in_sizes, int n_in,
                              void* d_out, int out_size, void* d_ws, size_t ws_size,
                              hipStream_t stream) {
    const float* vocab_ds = (const float*)d_in[0];
    const float* attns    = (const float*)d_in[1];
    const float* p_gens   = (const float*)d_in[2];
    const int*   sources  = (const int*)d_in[3];
    const int rows = in_sizes[2];
    const int V    = in_sizes[0] / rows;
    const int L    = in_sizes[1] / rows;
    const int B    = in_sizes[3] / L;
    float* out = (float*)d_out;

    const size_t mask_bytes = (size_t)L * (size_t)B * sizeof(int);
    if (ws_size >= mask_bytes) {
        int* vlast = (int*)d_ws;
        const int CPR = 8;   // 2048 rows * 8 = 16384 blocks = 64/CU
        mask_kernel<<<B, 256, 0, stream>>>(sources, vlast, L, B);
        scale_kernel<<<rows * CPR, 256, 0, stream>>>(vocab_ds, p_gens, out, V, CPR);
        scatter_kernel<<<rows, 256, 0, stream>>>(vocab_ds, attns, p_gens,
                                                 vlast, out, V, L, B);
    } else {
        fused_fallback_kernel<<<rows, 256, 0, stream>>>(
            vocab_ds, attns, p_gens, sources, out, V, L, B);
    }
}

// Round 5
// 262.742 us; speedup vs baseline: 1.0269x; 1.0269x over previous
//
#include <hip/hip_runtime.h>

typedef float f32x4 __attribute__((ext_vector_type(4)));

// ---------------------------------------------------------------------------
// Kernel A: per source column b, mark last occurrence of each vocab id.
// vlast[l*B+b] = sources[l*B+b] if l is the LAST occurrence of that id in
// column b, else -1. Break-free fixed-trip scan so LDS reads pipeline.
// ---------------------------------------------------------------------------
#define LMAX 1024

__global__ __launch_bounds__(256) void mask_kernel(
    const int* __restrict__ sources, int* __restrict__ vlast, int L, int B)
{
    const int b = blockIdx.x;
    __shared__ int s_col[LMAX];
    const bool use_lds = (L <= LMAX);
    if (use_lds) {
        for (int l = threadIdx.x; l < L; l += 256)
            s_col[l] = sources[(size_t)l * B + b];
    }
    __syncthreads();
    for (int l = threadIdx.x; l < L; l += 256) {
        const int v = use_lds ? s_col[l] : sources[(size_t)l * B + b];
        int dup = 0;
        if (use_lds) {
#pragma unroll 4
            for (int l2 = l + 1; l2 < L; ++l2)
                dup |= (s_col[l2] == v);
        } else {
            for (int l2 = l + 1; l2 < L; ++l2)
                dup |= (sources[(size_t)l2 * B + b] == v);
        }
        vlast[(size_t)l * B + b] = dup ? -1 : v;
    }
}

// ---------------------------------------------------------------------------
// Kernel B: streaming scale  out[row,:] = pg[row] * vd[row,:]
// Occupancy-capped: 65 KB dummy LDS -> exactly 2 blocks/CU (8 waves/CU).
// 512 blocks x 4 rows each, 4x-unrolled independent f32x4 loads, plain
// stores. Theory: fillBuffer hits 6.8 TB/s at ~3 waves/CU; fewer resident
// waves -> less read/write queue interleave, while 8 waves x 4 KB in flight
// (32 KB/CU) still exceeds the 9.2 KB BW*latency requirement.
// ---------------------------------------------------------------------------
#define SCALE_BLOCKS 512

__global__ __launch_bounds__(256) void scale_kernel(
    const float* __restrict__ vd, const float* __restrict__ pgs,
    float* __restrict__ out, int V, int rows, int rpb)
{
    __shared__ float lds_cap[16640];              // 65 KB -> 2 blocks/CU
    if (blockIdx.x > 0x7FFFFFF0u) {               // never true; keeps LDS alive
        lds_cap[threadIdx.x] = pgs[0];
        out[0] = lds_cap[0];
    }
    const int tid = threadIdx.x;
    const int r0 = blockIdx.x * rpb;
    const int r1 = (r0 + rpb < rows) ? (r0 + rpb) : rows;

    for (int row = r0; row < r1; ++row) {
        const size_t base = (size_t)row * (size_t)V;
        const float pg = pgs[row];

        // peel to 16B alignment (V odd -> base mod 4 rotates per row)
        const int mis  = (int)(base & 3);
        const int pre  = mis ? (4 - mis) : 0;
        const int preN = pre < V ? pre : V;
        if (tid < preN)
            out[base + tid] = pg * vd[base + tid];

        const int nvec = (V - preN) >> 2;
        const f32x4* __restrict__ v4 = (const f32x4*)(vd + base + preN);
        f32x4* __restrict__ o4       = (f32x4*)(out + base + preN);

        int i = tid;
        for (; i + 768 < nvec; i += 1024) {
            f32x4 a = v4[i];
            f32x4 b = v4[i + 256];
            f32x4 c = v4[i + 512];
            f32x4 d = v4[i + 768];
            a *= pg; b *= pg; c *= pg; d *= pg;
            o4[i]       = a;
            o4[i + 256] = b;
            o4[i + 512] = c;
            o4[i + 768] = d;
        }
        for (; i < nvec; i += 256) {
            f32x4 a = v4[i];
            a *= pg;
            o4[i] = a;
        }
        for (int j = preN + (nvec << 2) + tid; j < V; j += 256)
            out[base + j] = pg * vd[base + j];
    }
}

// ---------------------------------------------------------------------------
// Kernel C: scatter. Mask guarantees one writer per (row, vocab slot):
// out[row, v] = pg*vd[row, v] + (1-pg)*attns[row, l].
// ---------------------------------------------------------------------------
__global__ __launch_bounds__(256) void scatter_kernel(
    const float* __restrict__ vd, const float* __restrict__ attns,
    const float* __restrict__ pgs, const int* __restrict__ vlast,
    float* __restrict__ out, int V, int L, int B)
{
    const int row = blockIdx.x;
    const int b = row % B;
    const float pg = pgs[row];
    const float gate = 1.0f - pg;
    const size_t base = (size_t)row * (size_t)V;
    for (int l = threadIdx.x; l < L; l += 256) {
        const int v = vlast[(size_t)l * B + b];
        if (v >= 0 && v < V)
            out[base + v] = fmaf(pg, vd[base + v],
                                 gate * attns[(size_t)row * L + l]);
    }
}

// ---------------------------------------------------------------------------
// Fallback (round-1 fused kernel) if d_ws is too small for the mask.
// ---------------------------------------------------------------------------
__global__ __launch_bounds__(256) void fused_fallback_kernel(
    const float* __restrict__ vocab_ds, const float* __restrict__ attns,
    const float* __restrict__ p_gens, const int* __restrict__ sources,
    float* __restrict__ out, int V, int L, int B)
{
    const int row = blockIdx.x;
    const int tid = threadIdx.x;
    const size_t base = (size_t)row * (size_t)V;
    const float pg = p_gens[row];

    const int mis  = (int)(base & 3);
    const int pre  = mis ? (4 - mis) : 0;
    const int preN = pre < V ? pre : V;
    for (int j = tid; j < preN; j += blockDim.x)
        out[base + j] = pg * vocab_ds[base + j];
    const int nvec = (V - preN) >> 2;
    const f32x4* __restrict__ v4 = (const f32x4*)(vocab_ds + base + preN);
    f32x4* __restrict__ o4       = (f32x4*)(out + base + preN);
    for (int i = tid; i < nvec; i += blockDim.x) {
        f32x4 x = v4[i];
        x *= pg;
        o4[i] = x;
    }
    for (int j = preN + (nvec << 2) + tid; j < V; j += blockDim.x)
        out[base + j] = pg * vocab_ds[base + j];

    __shared__ int s_src[512];
    const int b = row % B;
    const bool use_lds = (L <= 512);
    if (use_lds) {
        for (int l = tid; l < L; l += blockDim.x)
            s_src[l] = sources[(size_t)l * B + b];
    }
    __syncthreads();
    const float gate = 1.0f - pg;
    for (int l = tid; l < L; l += blockDim.x) {
        const int v = use_lds ? s_src[l] : sources[(size_t)l * B + b];
        if (v < 0 || v >= V) continue;
        bool last = true;
        for (int l2 = l + 1; l2 < L; ++l2) {
            const int v2 = use_lds ? s_src[l2] : sources[(size_t)l2 * B + b];
            if (v2 == v) { last = false; break; }
        }
        if (last) {
            const float a = gate * attns[(size_t)row * L + l];
            out[base + v] = pg * vocab_ds[base + v] + a;
        }
    }
}

extern "C" void kernel_launch(void* const* d_in, const int* in_sizes, int n_in,
                              void* d_out, int out_size, void* d_ws, size_t ws_size,
                              hipStream_t stream) {
    const float* vocab_ds = (const float*)d_in[0];
    const float* attns    = (const float*)d_in[1];
    const float* p_gens   = (const float*)d_in[2];
    const int*   sources  = (const int*)d_in[3];
    const int rows = in_sizes[2];
    const int V    = in_sizes[0] / rows;
    const int L    = in_sizes[1] / rows;
    const int B    = in_sizes[3] / L;
    float* out = (float*)d_out;

    const size_t mask_bytes = (size_t)L * (size_t)B * sizeof(int);
    if (ws_size >= mask_bytes) {
        int* vlast = (int*)d_ws;
        const int nblk = (rows < SCALE_BLOCKS) ? rows : SCALE_BLOCKS;
        const int rpb  = (rows + nblk - 1) / nblk;
        mask_kernel<<<B, 256, 0, stream>>>(sources, vlast, L, B);
        scale_kernel<<<nblk, 256, 0, stream>>>(vocab_ds, p_gens, out, V, rows, rpb);
        scatter_kernel<<<rows, 256, 0, stream>>>(vocab_ds, attns, p_gens,
                                                 vlast, out, V, L, B);
    } else {
        fused_fallback_kernel<<<rows, 256, 0, stream>>>(
            vocab_ds, attns, p_gens, sources, out, V, L, B);
    }
}

// Round 6
// 234.371 us; speedup vs baseline: 1.1512x; 1.1210x over previous
//
#include <hip/hip_runtime.h>

typedef float f32x4 __attribute__((ext_vector_type(4)));
typedef unsigned int uint32;

#define MAXV 51200            // bitmap capacity; V=50257 fits
#define NWMAX (MAXV / 32 + 1) // 1601 words (+1 pad for spanning reads)
#define LPAD 1024             // sorted-list capacity (L=400 fits)

// ---------------------------------------------------------------------------
// Prep: per source column b, sort (v, l) pairs ascending by (v, l) via O(L^2)
// rank sort. Row-independent (rows share columns mod B). Last-occurrence-wins
// falls out of upper_bound search later (max l sorts last among equal v).
// ---------------------------------------------------------------------------
__global__ __launch_bounds__(256) void sort_kernel(
    const int* __restrict__ sources, int* __restrict__ sv, int* __restrict__ sl,
    int L, int B, int V)
{
    const int b = blockIdx.x;
    __shared__ int s_col[LPAD];
    for (int l = threadIdx.x; l < L; l += 256) {
        const int v = sources[(size_t)l * B + b];
        s_col[l] = (v >= 0 && v < V) ? v : 0x7FFFFFFF;   // mode="drop"
    }
    __syncthreads();
    int* __restrict__ svb = sv + (size_t)b * L;
    int* __restrict__ slb = sl + (size_t)b * L;
    for (int l = threadIdx.x; l < L; l += 256) {
        const int v = s_col[l];
        int rank = 0;
        for (int k = 0; k < L; ++k) {
            const int vk = s_col[k];
            rank += (vk < v) || (vk == v && k < l);
        }
        svb[rank] = v;
        slb[rank] = l;
    }
}

// ---------------------------------------------------------------------------
// Fused single-pass: out[row,j] = pg*vd[row,j] (+ gate*attns[row,l] when j is
// a scattered slot; last occurrence wins). One block per row (R3's winning
// streaming config: NT stores, 4x unroll). Per-row LDS: vocab bitmap for O(1)
// reject + sorted column for binary-search lookup on the ~400 hits.
// ---------------------------------------------------------------------------
__global__ __launch_bounds__(256) void fused_kernel(
    const float* __restrict__ vd, const float* __restrict__ attns,
    const float* __restrict__ pgs, const int* __restrict__ sv,
    const int* __restrict__ sl, float* __restrict__ out, int V, int L, int B)
{
    const int row = blockIdx.x;
    const int tid = threadIdx.x;
    const int b   = row % B;

    __shared__ uint32 bm[NWMAX];
    __shared__ int    s_v[LPAD];
    __shared__ int    s_l[LPAD];
    __shared__ float  s_attn[LPAD];

    const int NW = (V + 31) >> 5;
    for (int w = tid; w < NW + 1; w += 256) bm[w] = 0u;
    const int* __restrict__ svb = sv + (size_t)b * L;
    const int* __restrict__ slb = sl + (size_t)b * L;
    for (int t = tid; t < LPAD; t += 256) {
        s_v[t]    = (t < L) ? svb[t] : 0x7FFFFFFF;
        s_l[t]    = (t < L) ? slb[t] : 0;
        s_attn[t] = (t < L) ? attns[(size_t)row * L + t] : 0.0f;
    }
    __syncthreads();
    for (int t = tid; t < L; t += 256) {
        const int v = s_v[t];
        if (v < V) atomicOr(&bm[v >> 5], 1u << (v & 31));
    }
    __syncthreads();

    const float pg   = pgs[row];
    const float gate = 1.0f - pg;
    const size_t base = (size_t)row * (size_t)V;

    // upper_bound(j) - 1 => last entry with s_v==j => max l => last-wins
    auto lookup = [&](int j) -> float {
        int lo = 0, hi = LPAD;
        while (lo < hi) {
            const int mid = (lo + hi) >> 1;
            if (s_v[mid] <= j) lo = mid + 1; else hi = mid;
        }
        return gate * s_attn[s_l[lo - 1]];
    };

    // peel to 16B alignment (V odd -> base mod 4 rotates per row)
    const int mis  = (int)(base & 3);
    const int pre  = mis ? (4 - mis) : 0;
    const int preN = pre < V ? pre : V;
    if (tid < preN) {
        const int j = tid;
        float x = pg * vd[base + j];
        if ((bm[j >> 5] >> (j & 31)) & 1u) x += lookup(j);
        __builtin_nontemporal_store(x, &out[base + j]);
    }

    const int nvec = (V - preN) >> 2;
    const f32x4* __restrict__ v4 = (const f32x4*)(vd + base + preN);
    f32x4* __restrict__ o4       = (f32x4*)(out + base + preN);

    auto proc = [&](int i) {
        f32x4 x = v4[i];
        x *= pg;
        const int j0 = preN + (i << 2);
        const int w  = j0 >> 5;
        const uint32 sh = (uint32)(j0 & 31);
        uint32 bits;
        if (sh <= 28u) bits = (bm[w] >> sh) & 0xFu;
        else           bits = ((bm[w] >> sh) | (bm[w + 1] << (32u - sh))) & 0xFu;
        if (bits) {
#pragma unroll
            for (int e = 0; e < 4; ++e)
                if ((bits >> e) & 1u) x[e] += lookup(j0 + e);
        }
        __builtin_nontemporal_store(x, &o4[i]);
    };

    int i = tid;
    for (; i + 768 < nvec; i += 1024) {
        proc(i); proc(i + 256); proc(i + 512); proc(i + 768);
    }
    for (; i < nvec; i += 256) proc(i);

    for (int j = preN + (nvec << 2) + tid; j < V; j += 256) {
        float x = pg * vd[base + j];
        if ((bm[j >> 5] >> (j & 31)) & 1u) x += lookup(j);
        __builtin_nontemporal_store(x, &out[base + j]);
    }
}

// ---------------------------------------------------------------------------
// Fallback (round-1 fused kernel, verified correct) if ws/V/L out of bounds.
// ---------------------------------------------------------------------------
__global__ __launch_bounds__(256) void fused_fallback_kernel(
    const float* __restrict__ vocab_ds, const float* __restrict__ attns,
    const float* __restrict__ p_gens, const int* __restrict__ sources,
    float* __restrict__ out, int V, int L, int B)
{
    const int row = blockIdx.x;
    const int tid = threadIdx.x;
    const size_t base = (size_t)row * (size_t)V;
    const float pg = p_gens[row];

    const int mis  = (int)(base & 3);
    const int pre  = mis ? (4 - mis) : 0;
    const int preN = pre < V ? pre : V;
    for (int j = tid; j < preN; j += blockDim.x)
        out[base + j] = pg * vocab_ds[base + j];
    const int nvec = (V - preN) >> 2;
    const f32x4* __restrict__ v4 = (const f32x4*)(vocab_ds + base + preN);
    f32x4* __restrict__ o4       = (f32x4*)(out + base + preN);
    for (int i = tid; i < nvec; i += blockDim.x) {
        f32x4 x = v4[i];
        x *= pg;
        o4[i] = x;
    }
    for (int j = preN + (nvec << 2) + tid; j < V; j += blockDim.x)
        out[base + j] = pg * vocab_ds[base + j];

    __shared__ int s_src[512];
    const int b = row % B;
    const bool use_lds = (L <= 512);
    if (use_lds) {
        for (int l = tid; l < L; l += blockDim.x)
            s_src[l] = sources[(size_t)l * B + b];
    }
    __syncthreads();
    const float gate = 1.0f - pg;
    for (int l = tid; l < L; l += blockDim.x) {
        const int v = use_lds ? s_src[l] : sources[(size_t)l * B + b];
        if (v < 0 || v >= V) continue;
        bool last = true;
        for (int l2 = l + 1; l2 < L; ++l2) {
            const int v2 = use_lds ? s_src[l2] : sources[(size_t)l2 * B + b];
            if (v2 == v) { last = false; break; }
        }
        if (last) {
            const float a = gate * attns[(size_t)row * L + l];
            out[base + v] = pg * vocab_ds[base + v] + a;
        }
    }
}

extern "C" void kernel_launch(void* const* d_in, const int* in_sizes, int n_in,
                              void* d_out, int out_size, void* d_ws, size_t ws_size,
                              hipStream_t stream) {
    const float* vocab_ds = (const float*)d_in[0];
    const float* attns    = (const float*)d_in[1];
    const float* p_gens   = (const float*)d_in[2];
    const int*   sources  = (const int*)d_in[3];
    const int rows = in_sizes[2];
    const int V    = in_sizes[0] / rows;
    const int L    = in_sizes[1] / rows;
    const int B    = in_sizes[3] / L;
    float* out = (float*)d_out;

    const size_t need = (size_t)B * (size_t)L * 2 * sizeof(int);
    const bool fits = (ws_size >= need) && (V <= (NWMAX - 1) * 32) && (L <= LPAD);
    if (fits) {
        int* sv = (int*)d_ws;
        int* sl = sv + (size_t)B * (size_t)L;
        sort_kernel<<<B, 256, 0, stream>>>(sources, sv, sl, L, B, V);
        fused_kernel<<<rows, 256, 0, stream>>>(vocab_ds, attns, p_gens,
                                               sv, sl, out, V, L, B);
    } else {
        fused_fallback_kernel<<<rows, 256, 0, stream>>>(
            vocab_ds, attns, p_gens, sources, out, V, L, B);
    }
}